// Round 1
// baseline (170.200 us; speedup 1.0000x reference)
//
#include <hip/hip_runtime.h>

#define NROWS 8192      // B*T
#define KDIM  768       // F_IN
#define VSZ   320       // V
#define GSZ   2         // G
#define DSZ   128       // D
#define BM    32        // rows per block
#define BK    32        // K tile
#define XS_STRIDE 36    // BM + 4 pad
#define WT_STRIDE 324   // VSZ + 4 pad
#define XQ_TOTAL (NROWS * GSZ * DSZ)   // 2097152

// ---------------- zero accumulators (counts[640] + probs[640]) ----------------
__global__ __launch_bounds__(640) void zero_acc_k(float* __restrict__ acc) {
    const int t = threadIdx.x;
    acc[t] = 0.f;
    acc[t + GSZ * VSZ] = 0.f;
}

// ---------------- fused GEMM + argmax + softmax accumulation ----------------
// grid: (NROWS/BM)*GSZ blocks; block 256 threads.
// Each block: 32 rows x one group's 320 logits. K-transposed LDS tiles.
__global__ __launch_bounds__(256, 2) void fused_vq_k(
    const float* __restrict__ x, const float* __restrict__ W,
    const float* __restrict__ b, int* __restrict__ codes,
    float* __restrict__ counts, float* __restrict__ probs) {
    __shared__ float xs[BK][XS_STRIDE];
    __shared__ float wt[BK][WT_STRIDE];
    __shared__ float pacc[VSZ];

    const int tid  = threadIdx.x;
    const int g    = blockIdx.x & 1;
    const int row0 = (int)(blockIdx.x >> 1) * BM;
    const int tx   = tid & 15;   // col group: cols 4*(tx+16j)+q
    const int ty   = tid >> 4;   // row pair: rows 2*ty, 2*ty+1

    for (int i = tid; i < VSZ; i += 256) pacc[i] = 0.f;

    float acc[2][20];
#pragma unroll
    for (int j = 0; j < 20; ++j) { acc[0][j] = 0.f; acc[1][j] = 0.f; }

    const float* __restrict__ Wg = W + (size_t)g * VSZ * KDIM;

    const int lr  = tid >> 3;        // 0..31 (x-tile row)
    const int lkq = (tid & 7) * 4;   // 0,4,..,28 (k offset)

    for (int kt = 0; kt < KDIM; kt += BK) {
        __syncthreads();
        {   // stage x tile (transposed): 32 rows x 32 k
            const float4 v = *(const float4*)(x + (size_t)(row0 + lr) * KDIM + kt + lkq);
            xs[lkq + 0][lr] = v.x; xs[lkq + 1][lr] = v.y;
            xs[lkq + 2][lr] = v.z; xs[lkq + 3][lr] = v.w;
        }
#pragma unroll
        for (int p = 0; p < 10; ++p) {  // stage W tile (transposed): 320 cols x 32 k
            const int f  = tid + 256 * p;
            const int c  = f >> 3;
            const int kq = (f & 7) * 4;
            const float4 v = *(const float4*)(Wg + (size_t)c * KDIM + kt + kq);
            wt[kq + 0][c] = v.x; wt[kq + 1][c] = v.y;
            wt[kq + 2][c] = v.z; wt[kq + 3][c] = v.w;
        }
        __syncthreads();
#pragma unroll
        for (int k = 0; k < BK; ++k) {
            const float2 xv = *(const float2*)&xs[k][2 * ty];
#pragma unroll
            for (int j = 0; j < 5; ++j) {
                const float4 wv = *(const float4*)&wt[k][4 * (tx + 16 * j)];
                acc[0][4*j+0] += xv.x * wv.x;
                acc[0][4*j+1] += xv.x * wv.y;
                acc[0][4*j+2] += xv.x * wv.z;
                acc[0][4*j+3] += xv.x * wv.w;
                acc[1][4*j+0] += xv.y * wv.x;
                acc[1][4*j+1] += xv.y * wv.y;
                acc[1][4*j+2] += xv.y * wv.z;
                acc[1][4*j+3] += xv.y * wv.w;
            }
        }
    }

    // bias (b is zeros in this problem, but keep it exact)
#pragma unroll
    for (int j = 0; j < 5; ++j)
#pragma unroll
        for (int q = 0; q < 4; ++q) {
            const float bb = b[g * VSZ + 4 * (tx + 16 * j) + q];
            acc[0][4*j+q] += bb;
            acc[1][4*j+q] += bb;
        }

    // per-row argmax + softmax; each row owned by a contiguous aligned 16-lane group
#pragma unroll
    for (int i = 0; i < 2; ++i) {
        const int r = 2 * ty + i;
        float m = -3.4e38f; int am = 0x7fffffff;
#pragma unroll
        for (int j = 0; j < 5; ++j)
#pragma unroll
            for (int q = 0; q < 4; ++q) {
                const float l = acc[i][4*j+q];
                const int   c = 4 * (tx + 16 * j) + q;
                if (l > m) { m = l; am = c; }
            }
#pragma unroll
        for (int off = 8; off >= 1; off >>= 1) {
            const float om = __shfl_xor(m, off);
            const int   oa = __shfl_xor(am, off);
            if (om > m || (om == m && oa < am)) { m = om; am = oa; }
        }
        float s = 0.f;
#pragma unroll
        for (int j = 0; j < 20; ++j) {
            const float e = __expf(acc[i][j] - m);
            acc[i][j] = e;
            s += e;
        }
#pragma unroll
        for (int off = 8; off >= 1; off >>= 1) s += __shfl_xor(s, off);
        const float invs = 1.f / s;
        if (tx == 0) {
            const int gr = row0 + r;
            codes[gr * GSZ + g] = am;
            atomicAdd(&counts[g * VSZ + am], 1.f);
        }
#pragma unroll
        for (int j = 0; j < 5; ++j)
#pragma unroll
            for (int q = 0; q < 4; ++q)
                atomicAdd(&pacc[4 * (tx + 16 * j) + q], acc[i][4*j+q] * invs);
    }
    __syncthreads();
    for (int c = tid; c < VSZ; c += 256) atomicAdd(&probs[g * VSZ + c], pacc[c]);
}

// ---------------- gather xq = codebook[g, k] ----------------
__global__ __launch_bounds__(64) void gather_k(
    const float* __restrict__ codebook, const int* __restrict__ codes,
    float* __restrict__ out) {
    const int n  = blockIdx.x;
    const int t  = threadIdx.x;
    const int g  = t >> 5;
    const int d4 = (t & 31) * 4;
    const int k  = codes[n * GSZ + g];
    const float4 v = *(const float4*)(codebook + ((size_t)(g * VSZ + k)) * DSZ + d4);
    *(float4*)(out + (size_t)n * (GSZ * DSZ) + g * DSZ + d4) = v;
}

// ---------------- perplexities + constant ----------------
__global__ __launch_bounds__(640) void finalize_k(
    const float* __restrict__ counts, const float* __restrict__ probs,
    float* __restrict__ out_scalars) {
    __shared__ float se_c[GSZ], se_p[GSZ];
    const int t = threadIdx.x;         // 0..639, each 64-thread wave lies in one g
    if (t < GSZ) { se_c[t] = 0.f; se_p[t] = 0.f; }
    __syncthreads();
    const int g = t / VSZ;
    const float hp = counts[t] * (1.f / (float)NROWS);
    const float ap = probs[t]  * (1.f / (float)NROWS);
    float tc = hp * logf(hp + 1e-7f);
    float tp = ap * logf(ap + 1e-7f);
#pragma unroll
    for (int off = 32; off >= 1; off >>= 1) {
        tc += __shfl_xor(tc, off);
        tp += __shfl_xor(tp, off);
    }
    if ((t & 63) == 0) { atomicAdd(&se_c[g], tc); atomicAdd(&se_p[g], tp); }
    __syncthreads();
    if (t == 0) {
        out_scalars[0] = (float)(GSZ * VSZ);                 // 640
        out_scalars[1] = expf(-se_c[0]) + expf(-se_c[1]);    // code_perplexity
        out_scalars[2] = expf(-se_p[0]) + expf(-se_p[1]);    // prob_perplexity
    }
}

extern "C" void kernel_launch(void* const* d_in, const int* in_sizes, int n_in,
                              void* d_out, int out_size, void* d_ws, size_t ws_size,
                              hipStream_t stream) {
    const float* x        = (const float*)d_in[0];
    const float* W        = (const float*)d_in[1];
    const float* b        = (const float*)d_in[2];
    const float* codebook = (const float*)d_in[3];
    float* out = (float*)d_out;

    int*   codes  = (int*)d_ws;
    float* accf   = (float*)((char*)d_ws + (size_t)NROWS * GSZ * sizeof(int));
    float* counts = accf;
    float* probs  = accf + GSZ * VSZ;

    zero_acc_k<<<dim3(1), dim3(640), 0, stream>>>(accf);
    fused_vq_k<<<dim3((NROWS / BM) * GSZ), dim3(256), 0, stream>>>(x, W, b, codes, counts, probs);
    gather_k<<<dim3(NROWS), dim3(64), 0, stream>>>(codebook, codes, out);
    finalize_k<<<dim3(1), dim3(640), 0, stream>>>(counts, probs, out + XQ_TOTAL);
}

// Round 2
// 107.439 us; speedup vs baseline: 1.5842x; 1.5842x over previous
//
#include <hip/hip_runtime.h>
#include <hip/hip_bf16.h>

#define NROWS 8192      // B*T
#define KDIM  768       // F_IN
#define VSZ   320       // V
#define GSZ   2         // G
#define NCOL  640       // G*V
#define DSZ   128       // D
#define BM    32        // rows per block
#define XQ_TOTAL (NROWS * GSZ * DSZ)   // 2097152
#define MARGIN 1.5f

typedef __attribute__((ext_vector_type(8))) short bf16x8;
typedef __attribute__((ext_vector_type(4))) float f32x4;

static __device__ __forceinline__ short f2bf(float f) {
    union { __hip_bfloat16 h; short s; } u;
    u.h = __float2bfloat16(f);   // round-to-nearest-even
    return u.s;
}

// ---------------- zero accumulators (counts[640] + probs[640]) ----------------
__global__ __launch_bounds__(640) void zero_acc_k(float* __restrict__ acc) {
    const int t = threadIdx.x;
    acc[t] = 0.f;
    acc[t + NCOL] = 0.f;
}

// ---------------- W f32 -> bf16 prep ----------------
__global__ __launch_bounds__(512) void prep_w_k(const float* __restrict__ W,
                                                short* __restrict__ Wb) {
    const size_t i = ((size_t)blockIdx.x * 512 + threadIdx.x) * 8;
    const float4 a = *(const float4*)(W + i);
    const float4 c = *(const float4*)(W + i + 4);
    bf16x8 r;
    r[0] = f2bf(a.x); r[1] = f2bf(a.y); r[2] = f2bf(a.z); r[3] = f2bf(a.w);
    r[4] = f2bf(c.x); r[5] = f2bf(c.y); r[6] = f2bf(c.z); r[7] = f2bf(c.w);
    *(bf16x8*)(Wb + i) = r;
}

// ---------------- fused bf16-MFMA GEMM + argmax + softmax + fp32 refine ----------------
// grid 256 blocks (1/CU), 512 threads = 8 waves.
// Block: rows [blockIdx*32, +32) x all 640 cols.
// Wave w: wm=w>>2 (16-row half), wn=w&3 (160-col quarter), group g=wn>>1.
__global__ __launch_bounds__(512, 2) void fused_vq_k(
    const float* __restrict__ x, const short* __restrict__ Wb,
    const float* __restrict__ W, const float* __restrict__ b,
    int* __restrict__ codes, float* __restrict__ counts, float* __restrict__ probs) {

    __shared__ short xs[2][BM][72];      // 144B row stride: 16B-aligned, conflict-free
    __shared__ float pacc[NCOL];
    __shared__ float wmax[BM][2][2];
    __shared__ int   warg[BM][2][2];
    __shared__ float ssum[BM][2][2];
    __shared__ float rmax_s[BM][2];
    __shared__ int   rarg_s[BM][2];
    __shared__ int   cnt_s[BM][2];
    __shared__ int   list_s[BM][2][16];
    __shared__ int   work_s[64];
    __shared__ int   nwork_s;

    const int tid  = threadIdx.x;
    const int lane = tid & 63;
    const int w    = tid >> 6;
    const int wm   = w >> 2;
    const int wn   = w & 3;
    const int g    = wn >> 1;
    const int l15  = lane & 15;
    const int l4   = lane >> 4;
    const int row0 = blockIdx.x * BM;

    for (int i = tid; i < NCOL; i += 512) pacc[i] = 0.f;
    if (tid < 64) cnt_s[tid >> 1][tid & 1] = 0;
    if (tid == 0) nwork_s = 0;

    // B fragment base addresses (element index into Wb); statically indexed only
    size_t bbase[10];
#pragma unroll
    for (int n = 0; n < 10; ++n)
        bbase[n] = (size_t)(wn * 160 + n * 16 + l15) * KDIM + l4 * 8;

    // x staging mapping: 512 threads x float4 = 32 rows x 64 k per tile
    const int srow = tid >> 4;
    const int sk4  = (tid & 15) * 4;
    const float* xrowp = x + (size_t)(row0 + srow) * KDIM + sk4;

    f32x4 acc[10];
#pragma unroll
    for (int n = 0; n < 10; ++n) acc[n] = (f32x4){0.f, 0.f, 0.f, 0.f};

    // prologue: stage tile 0, preload B for k-step 0
    {
        const float4 sv = *(const float4*)(xrowp);
        const short t0 = f2bf(sv.x), t1 = f2bf(sv.y), t2 = f2bf(sv.z), t3 = f2bf(sv.w);
        const int lo = (t0 & 0xffff) | (t1 << 16);
        const int hi = (t2 & 0xffff) | (t3 << 16);
        *(int2*)&xs[0][srow][sk4] = make_int2(lo, hi);
    }
    bf16x8 bA[10], bB[10];
#pragma unroll
    for (int n = 0; n < 10; ++n) bA[n] = *(const bf16x8*)(Wb + bbase[n]);
    __syncthreads();

    const int arow = wm * 16 + l15;
    int buf = 0;
#pragma unroll 1
    for (int t = 0; t < 12; ++t) {
        const int kt = t * 64;
        float4 sv;
        if (t < 11) sv = *(const float4*)(xrowp + kt + 64);   // async-stage: issue early
        // step 0 (k = kt): consume bA, prefetch bB (k = kt+32)
#pragma unroll
        for (int n = 0; n < 10; ++n) bB[n] = *(const bf16x8*)(Wb + bbase[n] + kt + 32);
        {
            const bf16x8 a0 = *(const bf16x8*)&xs[buf][arow][l4 * 8];
#pragma unroll
            for (int n = 0; n < 10; ++n)
                acc[n] = __builtin_amdgcn_mfma_f32_16x16x32_bf16(a0, bA[n], acc[n], 0, 0, 0);
        }
        // step 1 (k = kt+32): consume bB, prefetch bA (k = kt+64)
        if (t < 11) {
#pragma unroll
            for (int n = 0; n < 10; ++n) bA[n] = *(const bf16x8*)(Wb + bbase[n] + kt + 64);
        }
        {
            const bf16x8 a1 = *(const bf16x8*)&xs[buf][arow][32 + l4 * 8];
#pragma unroll
            for (int n = 0; n < 10; ++n)
                acc[n] = __builtin_amdgcn_mfma_f32_16x16x32_bf16(a1, bB[n], acc[n], 0, 0, 0);
        }
        if (t < 11) {  // write staged tile (loads have had the MFMA phase to land)
            const short t0 = f2bf(sv.x), t1 = f2bf(sv.y), t2 = f2bf(sv.z), t3 = f2bf(sv.w);
            const int lo = (t0 & 0xffff) | (t1 << 16);
            const int hi = (t2 & 0xffff) | (t3 << 16);
            *(int2*)&xs[buf ^ 1][srow][sk4] = make_int2(lo, hi);
        }
        __syncthreads();
        buf ^= 1;
    }

    // bias
#pragma unroll
    for (int n = 0; n < 10; ++n) {
        const float bv = b[wn * 160 + n * 16 + l15];
#pragma unroll
        for (int r = 0; r < 4; ++r) acc[n][r] += bv;
    }

    // E1: per-row wave-local max/argmax (rows: wm*16 + l4*4 + r; cols: wn*160 + n*16 + l15)
    float m4[4]; int a4[4];
#pragma unroll
    for (int r = 0; r < 4; ++r) { m4[r] = -3.4e38f; a4[r] = 0x7fffffff; }
#pragma unroll
    for (int n = 0; n < 10; ++n) {
        const int col = wn * 160 + n * 16 + l15;
#pragma unroll
        for (int r = 0; r < 4; ++r) {
            const float v = acc[n][r];
            if (v > m4[r]) { m4[r] = v; a4[r] = col; }
        }
    }
#pragma unroll
    for (int off = 8; off >= 1; off >>= 1)
#pragma unroll
        for (int r = 0; r < 4; ++r) {
            const float om = __shfl_xor(m4[r], off);
            const int   oa = __shfl_xor(a4[r], off);
            if (om > m4[r] || (om == m4[r] && oa < a4[r])) { m4[r] = om; a4[r] = oa; }
        }
    if (l15 == 0)
#pragma unroll
        for (int r = 0; r < 4; ++r) {
            const int row = wm * 16 + l4 * 4 + r;
            wmax[row][g][wn & 1] = m4[r];
            warg[row][g][wn & 1] = a4[r];
        }
    __syncthreads();

    // E2a: combine the two col-halves -> row max over 320
    if (tid < 64) {
        const int row = tid >> 1, gg = tid & 1;
        const float m0 = wmax[row][gg][0], m1 = wmax[row][gg][1];
        const int   c0 = warg[row][gg][0], c1 = warg[row][gg][1];
        if (m0 > m1 || (m0 == m1 && c0 < c1)) { rmax_s[row][gg] = m0; rarg_s[row][gg] = c0; }
        else                                  { rmax_s[row][gg] = m1; rarg_s[row][gg] = c1; }
    }
    __syncthreads();

    // E2b: candidate scan (within MARGIN of max) + exp + denom partial
    float rm[4];
#pragma unroll
    for (int r = 0; r < 4; ++r) rm[r] = rmax_s[wm * 16 + l4 * 4 + r][g];
    float sden[4] = {0.f, 0.f, 0.f, 0.f};
#pragma unroll
    for (int n = 0; n < 10; ++n) {
        const int col = wn * 160 + n * 16 + l15;
#pragma unroll
        for (int r = 0; r < 4; ++r) {
            const float v = acc[n][r];
            if (v > rm[r] - MARGIN) {
                const int row = wm * 16 + l4 * 4 + r;
                const int idx = atomicAdd(&cnt_s[row][g], 1);
                if (idx < 16) list_s[row][g][idx] = col;
            }
            const float e = __expf(v - rm[r]);
            acc[n][r] = e;
            sden[r] += e;
        }
    }
#pragma unroll
    for (int off = 8; off >= 1; off >>= 1)
#pragma unroll
        for (int r = 0; r < 4; ++r) sden[r] += __shfl_xor(sden[r], off);
    if (l15 == 0)
#pragma unroll
        for (int r = 0; r < 4; ++r) ssum[wm * 16 + l4 * 4 + r][g][wn & 1] = sden[r];
    __syncthreads();

    // E3: single-candidate fast path writes codes/counts; multi-candidate -> worklist
    if (tid < 64) {
        const int row = tid >> 1, gg = tid & 1;
        const int grow = row0 + row;
        if (cnt_s[row][gg] <= 1) {
            const int col = rarg_s[row][gg];
            codes[grow * 2 + gg] = col;
            atomicAdd(&counts[col], 1.f);
        } else {
            const int wi = atomicAdd(&nwork_s, 1);
            work_s[wi] = row * 2 + gg;
        }
    }
    __syncthreads();

    // E5: softmax col-sums into pacc
    float inv[4];
#pragma unroll
    for (int r = 0; r < 4; ++r) {
        const int row = wm * 16 + l4 * 4 + r;
        inv[r] = 1.f / (ssum[row][g][0] + ssum[row][g][1]);
    }
#pragma unroll
    for (int n = 0; n < 10; ++n) {
        float pc = acc[n][0] * inv[0] + acc[n][1] * inv[1] + acc[n][2] * inv[2] + acc[n][3] * inv[3];
        pc += __shfl_xor(pc, 16);
        pc += __shfl_xor(pc, 32);
        if (l4 == 0) atomicAdd(&pacc[wn * 160 + n * 16 + l15], pc);
    }

    // E4: fp32-exact refinement, one wave per pending (row,g)
    const int nwork = nwork_s;
    for (int it = w; it < nwork; it += 8) {
        const int rg = work_s[it];
        const int row = rg >> 1, gg = rg & 1;
        const int grow = row0 + row;
        const int nc = min(cnt_s[row][gg], 16);
        float bestv = -3.4e38f; int bestc = 0x7fffffff;
        for (int ci = 0; ci < nc; ++ci) {
            const int col = list_s[row][gg][ci];
            float p = 0.f;
            for (int j = lane; j < KDIM; j += 64)
                p += x[(size_t)grow * KDIM + j] * W[(size_t)col * KDIM + j];
#pragma unroll
            for (int off = 32; off >= 1; off >>= 1) p += __shfl_xor(p, off);
            p += b[col];
            if (p > bestv || (p == bestv && col < bestc)) { bestv = p; bestc = col; }
        }
        if (lane == 0) {
            codes[grow * 2 + gg] = bestc;
            atomicAdd(&counts[bestc], 1.f);
        }
    }
    __syncthreads();

    // E6: flush block-local prob sums
    for (int c = tid; c < NCOL; c += 512) atomicAdd(&probs[c], pacc[c]);
}

// ---------------- gather xq = codebook[code] ----------------
__global__ __launch_bounds__(256) void gather_k(
    const float* __restrict__ codebook, const int* __restrict__ codes,
    float* __restrict__ out) {
    const int t  = blockIdx.x * 256 + threadIdx.x;   // 8192*32 threads
    const int n  = t >> 5;
    const int c  = t & 31;
    const int gg = c >> 4;
    const int d8 = (c & 15) * 8;
    const int k  = codes[n * 2 + gg];                // global col indexes codebook rows
    const float4 v0 = *(const float4*)(codebook + (size_t)k * DSZ + d8);
    const float4 v1 = *(const float4*)(codebook + (size_t)k * DSZ + d8 + 4);
    float* op = out + (size_t)n * (GSZ * DSZ) + gg * DSZ + d8;
    *(float4*)op = v0;
    *(float4*)(op + 4) = v1;
}

// ---------------- perplexities + constant ----------------
__global__ __launch_bounds__(640) void finalize_k(
    const float* __restrict__ counts, const float* __restrict__ probs,
    float* __restrict__ out_scalars) {
    __shared__ float se_c[GSZ], se_p[GSZ];
    const int t = threadIdx.x;
    if (t < GSZ) { se_c[t] = 0.f; se_p[t] = 0.f; }
    __syncthreads();
    const int g = t / VSZ;
    const float hp = counts[t] * (1.f / (float)NROWS);
    const float ap = probs[t]  * (1.f / (float)NROWS);
    float tc = hp * logf(hp + 1e-7f);
    float tp = ap * logf(ap + 1e-7f);
#pragma unroll
    for (int off = 32; off >= 1; off >>= 1) {
        tc += __shfl_xor(tc, off);
        tp += __shfl_xor(tp, off);
    }
    if ((t & 63) == 0) { atomicAdd(&se_c[g], tc); atomicAdd(&se_p[g], tp); }
    __syncthreads();
    if (t == 0) {
        out_scalars[0] = (float)NCOL;
        out_scalars[1] = expf(-se_c[0]) + expf(-se_c[1]);
        out_scalars[2] = expf(-se_p[0]) + expf(-se_p[1]);
    }
}

extern "C" void kernel_launch(void* const* d_in, const int* in_sizes, int n_in,
                              void* d_out, int out_size, void* d_ws, size_t ws_size,
                              hipStream_t stream) {
    const float* x        = (const float*)d_in[0];
    const float* W        = (const float*)d_in[1];
    const float* b        = (const float*)d_in[2];
    const float* codebook = (const float*)d_in[3];
    float* out = (float*)d_out;

    short* Wb     = (short*)d_ws;                                    // 983040 B
    int*   codes  = (int*)((char*)d_ws + 983040);                    // 65536 B
    float* accf   = (float*)((char*)d_ws + 983040 + 65536);          // counts+probs
    float* counts = accf;
    float* probs  = accf + NCOL;

    zero_acc_k<<<dim3(1), dim3(640), 0, stream>>>(accf);
    prep_w_k<<<dim3(120), dim3(512), 0, stream>>>(W, Wb);
    fused_vq_k<<<dim3(NROWS / BM), dim3(512), 0, stream>>>(x, Wb, W, b, codes, counts, probs);
    gather_k<<<dim3(NROWS * 32 / 256), dim3(256), 0, stream>>>(codebook, codes, out);
    finalize_k<<<dim3(1), dim3(640), 0, stream>>>(counts, probs, out + XQ_TOTAL);
}

// Round 3
// 78.759 us; speedup vs baseline: 2.1610x; 1.3641x over previous
//
#include <hip/hip_runtime.h>
#include <hip/hip_bf16.h>

#define NROWS 8192      // B*T
#define KDIM  768       // F_IN
#define VSZ   320       // V
#define GSZ   2         // G
#define NCOL  640       // G*V
#define DSZ   128       // D
#define BM    32        // rows per block
#define XQ_TOTAL (NROWS * GSZ * DSZ)   // 2097152
#define MARGIN 1.5f
#define XS_STRIDE 776   // 768 + 8 shorts -> 1552B row stride (4-bank skew, conflict-free)

typedef __attribute__((ext_vector_type(8))) short bf16x8;
typedef __attribute__((ext_vector_type(4))) float f32x4;

static __device__ __forceinline__ short f2bf(float f) {
    union { __hip_bfloat16 h; short s; } u;
    u.h = __float2bfloat16(f);   // round-to-nearest-even
    return u.s;
}

// ---------------- W f32 -> bf16 prep (+ zero counts/probs accumulators) ----------------
__global__ __launch_bounds__(512) void prep_w_k(const float* __restrict__ W,
                                                short* __restrict__ Wb,
                                                float* __restrict__ acc) {
    if (blockIdx.x == 0)
        for (int i = threadIdx.x; i < 2 * NCOL; i += 512) acc[i] = 0.f;
    const size_t i = ((size_t)blockIdx.x * 512 + threadIdx.x) * 8;
    const float4 a = *(const float4*)(W + i);
    const float4 c = *(const float4*)(W + i + 4);
    bf16x8 r;
    r[0] = f2bf(a.x); r[1] = f2bf(a.y); r[2] = f2bf(a.z); r[3] = f2bf(a.w);
    r[4] = f2bf(c.x); r[5] = f2bf(c.y); r[6] = f2bf(c.z); r[7] = f2bf(c.w);
    *(bf16x8*)(Wb + i) = r;
}

// ---------------- fused bf16-MFMA GEMM + argmax + softmax + fp32 refine + gather ----------------
// grid 256 blocks (1/CU), 512 threads = 8 waves.
// Block: rows [blockIdx*32, +32) x all 640 cols. Wave w owns cols [80w, 80w+80), all 32 rows.
// x-tile fully staged in LDS (one barrier); K-loop is barrier-free; B loaded once per block.
__global__ __launch_bounds__(512, 2) void fused_vq_k(
    const float* __restrict__ x, const short* __restrict__ Wb,
    const float* __restrict__ W, const float* __restrict__ b,
    const float* __restrict__ codebook,
    float* __restrict__ counts, float* __restrict__ probs,
    float* __restrict__ xq) {

    __shared__ short xs[BM][XS_STRIDE];      // 49664 B
    __shared__ float wmax[BM][8];
    __shared__ int   warg[BM][8];
    __shared__ float ssum[BM][8];
    __shared__ float rmax_s[BM][2];
    __shared__ int   rarg_s[BM][2];
    __shared__ int   cnt_s[BM][2];
    __shared__ int   list_s[BM][2][16];
    __shared__ int   code_s[BM][2];
    __shared__ int   work_s[64];
    __shared__ int   nwork_s;

    const int tid  = threadIdx.x;
    const int lane = tid & 63;
    const int w    = tid >> 6;       // wave 0..7
    const int g    = w >> 2;         // group
    const int l15  = lane & 15;
    const int l4   = lane >> 4;      // 0..3
    const int row0 = blockIdx.x * BM;

    if (tid < 64) cnt_s[tid >> 1][tid & 1] = 0;
    if (tid == 0) nwork_s = 0;

    // ---- stage full x tile as bf16: 32 rows x 768 k ----
    {
        const int srow = tid >> 4;
        const int sk   = (tid & 15) * 4;
        const float* xp = x + (size_t)(row0 + srow) * KDIM + sk;
#pragma unroll
        for (int t = 0; t < 12; ++t) {
            const float4 v = *(const float4*)(xp + t * 64);
            const short t0 = f2bf(v.x), t1 = f2bf(v.y), t2 = f2bf(v.z), t3 = f2bf(v.w);
            const int lo = (t0 & 0xffff) | (t1 << 16);
            const int hi = (t2 & 0xffff) | (t3 << 16);
            *(int2*)&xs[srow][t * 64 + sk] = make_int2(lo, hi);
        }
    }

    // B fragment bases: col(n) = 80w + 16n + l15, k-offset l4*8
    int bbase[5];
#pragma unroll
    for (int n = 0; n < 5; ++n)
        bbase[n] = (w * 80 + n * 16 + l15) * KDIM + l4 * 8;

    f32x4 acc0[5], acc1[5];
#pragma unroll
    for (int n = 0; n < 5; ++n) {
        acc0[n] = (f32x4){0.f, 0.f, 0.f, 0.f};
        acc1[n] = (f32x4){0.f, 0.f, 0.f, 0.f};
    }

    bf16x8 cur[5], nxt[5];
#pragma unroll
    for (int n = 0; n < 5; ++n) cur[n] = *(const bf16x8*)(Wb + bbase[n]);

    __syncthreads();   // the only pre-epilogue barrier

    // ---- barrier-free K loop: 12 x (two 32-k steps) ----
#pragma unroll 1
    for (int s2 = 0; s2 < 12; ++s2) {
        const int k0 = s2 * 64;
#pragma unroll
        for (int n = 0; n < 5; ++n) nxt[n] = *(const bf16x8*)(Wb + bbase[n] + k0 + 32);
        {
            const bf16x8 a0 = *(const bf16x8*)&xs[l15][k0 + l4 * 8];
            const bf16x8 a1 = *(const bf16x8*)&xs[16 + l15][k0 + l4 * 8];
#pragma unroll
            for (int n = 0; n < 5; ++n) {
                acc0[n] = __builtin_amdgcn_mfma_f32_16x16x32_bf16(a0, cur[n], acc0[n], 0, 0, 0);
                acc1[n] = __builtin_amdgcn_mfma_f32_16x16x32_bf16(a1, cur[n], acc1[n], 0, 0, 0);
            }
        }
        if (s2 < 11) {
#pragma unroll
            for (int n = 0; n < 5; ++n) cur[n] = *(const bf16x8*)(Wb + bbase[n] + k0 + 64);
        }
        {
            const bf16x8 a0 = *(const bf16x8*)&xs[l15][k0 + 32 + l4 * 8];
            const bf16x8 a1 = *(const bf16x8*)&xs[16 + l15][k0 + 32 + l4 * 8];
#pragma unroll
            for (int n = 0; n < 5; ++n) {
                acc0[n] = __builtin_amdgcn_mfma_f32_16x16x32_bf16(a0, nxt[n], acc0[n], 0, 0, 0);
                acc1[n] = __builtin_amdgcn_mfma_f32_16x16x32_bf16(a1, nxt[n], acc1[n], 0, 0, 0);
            }
        }
    }

    // bias (zeros in this problem, kept exact)
#pragma unroll
    for (int n = 0; n < 5; ++n) {
        const float bv = b[w * 80 + n * 16 + l15];
#pragma unroll
        for (int r = 0; r < 4; ++r) { acc0[n][r] += bv; acc1[n][r] += bv; }
    }

    // E1: wave-local per-row max/argmax over this wave's 80 cols
    // rows: h*16 + l4*4 + r ; cols: 80w + 16n + l15
    float m2[2][4]; int a2[2][4];
#pragma unroll
    for (int h = 0; h < 2; ++h)
#pragma unroll
        for (int r = 0; r < 4; ++r) { m2[h][r] = -3.4e38f; a2[h][r] = 0x7fffffff; }
#pragma unroll
    for (int n = 0; n < 5; ++n) {
        const int col = w * 80 + n * 16 + l15;
#pragma unroll
        for (int r = 0; r < 4; ++r) {
            float v = acc0[n][r];
            if (v > m2[0][r]) { m2[0][r] = v; a2[0][r] = col; }
            v = acc1[n][r];
            if (v > m2[1][r]) { m2[1][r] = v; a2[1][r] = col; }
        }
    }
#pragma unroll
    for (int off = 8; off >= 1; off >>= 1)
#pragma unroll
        for (int h = 0; h < 2; ++h)
#pragma unroll
            for (int r = 0; r < 4; ++r) {
                const float om = __shfl_xor(m2[h][r], off);
                const int   oa = __shfl_xor(a2[h][r], off);
                if (om > m2[h][r] || (om == m2[h][r] && oa < a2[h][r])) { m2[h][r] = om; a2[h][r] = oa; }
            }
    if (l15 == 0)
#pragma unroll
        for (int h = 0; h < 2; ++h)
#pragma unroll
            for (int r = 0; r < 4; ++r) {
                const int row = h * 16 + l4 * 4 + r;
                wmax[row][w] = m2[h][r];
                warg[row][w] = a2[h][r];
            }
    __syncthreads();

    // E2a: combine 4 wave-quarters per group -> row max over 320
    if (tid < 64) {
        const int row = tid >> 1, gg = tid & 1;
        float m = -3.4e38f; int c = 0x7fffffff;
#pragma unroll
        for (int q = 0; q < 4; ++q) {
            const float mq = wmax[row][gg * 4 + q];
            const int   cq = warg[row][gg * 4 + q];
            if (mq > m || (mq == m && cq < c)) { m = mq; c = cq; }
        }
        rmax_s[row][gg] = m;
        rarg_s[row][gg] = c;
    }
    __syncthreads();

    // E2b: candidate scan + exp + denominator partials
    float rm[2][4];
#pragma unroll
    for (int h = 0; h < 2; ++h)
#pragma unroll
        for (int r = 0; r < 4; ++r) rm[h][r] = rmax_s[h * 16 + l4 * 4 + r][g];
    float sden[2][4] = {{0.f,0.f,0.f,0.f},{0.f,0.f,0.f,0.f}};
#pragma unroll
    for (int n = 0; n < 5; ++n) {
        const int col = w * 80 + n * 16 + l15;
#pragma unroll
        for (int h = 0; h < 2; ++h)
#pragma unroll
            for (int r = 0; r < 4; ++r) {
                const float v = h ? acc1[n][r] : acc0[n][r];
                if (v > rm[h][r] - MARGIN) {
                    const int row = h * 16 + l4 * 4 + r;
                    const int idx = atomicAdd(&cnt_s[row][g], 1);
                    if (idx < 16) list_s[row][g][idx] = col;
                }
                const float e = __expf(v - rm[h][r]);
                if (h) acc1[n][r] = e; else acc0[n][r] = e;
                sden[h][r] += e;
            }
    }
#pragma unroll
    for (int off = 8; off >= 1; off >>= 1)
#pragma unroll
        for (int h = 0; h < 2; ++h)
#pragma unroll
            for (int r = 0; r < 4; ++r) sden[h][r] += __shfl_xor(sden[h][r], off);
    if (l15 == 0)
#pragma unroll
        for (int h = 0; h < 2; ++h)
#pragma unroll
            for (int r = 0; r < 4; ++r) ssum[h * 16 + l4 * 4 + r][w] = sden[h][r];
    __syncthreads();

    // E3: single-candidate fast path; multi-candidate -> worklist
    if (tid < 64) {
        const int row = tid >> 1, gg = tid & 1;
        if (cnt_s[row][gg] <= 1) {
            const int col = rarg_s[row][gg];
            code_s[row][gg] = col;
            atomicAdd(&counts[col], 1.f);
        } else {
            const int wi = atomicAdd(&nwork_s, 1);
            work_s[wi] = row * 2 + gg;
        }
    }
    __syncthreads();

    // E5: softmax column sums -> global probs (each col owned by exactly one wave)
    float inv[2][4];
#pragma unroll
    for (int h = 0; h < 2; ++h)
#pragma unroll
        for (int r = 0; r < 4; ++r) {
            const int row = h * 16 + l4 * 4 + r;
            inv[h][r] = 1.f / (ssum[row][g * 4] + ssum[row][g * 4 + 1] +
                               ssum[row][g * 4 + 2] + ssum[row][g * 4 + 3]);
        }
#pragma unroll
    for (int n = 0; n < 5; ++n) {
        float pc = 0.f;
#pragma unroll
        for (int r = 0; r < 4; ++r)
            pc += acc0[n][r] * inv[0][r] + acc1[n][r] * inv[1][r];
        pc += __shfl_xor(pc, 16);
        pc += __shfl_xor(pc, 32);
        if (l4 == 0) atomicAdd(&probs[w * 80 + n * 16 + l15], pc);
    }

    // E4: fp32-exact refinement, one wave per pending (row,g)
    const int nwork = nwork_s;
    for (int it = w; it < nwork; it += 8) {
        const int rg = work_s[it];
        const int row = rg >> 1, gg = rg & 1;
        const int grow = row0 + row;
        const int nc = min(cnt_s[row][gg], 16);
        float bestv = -3.4e38f; int bestc = 0x7fffffff;
        for (int ci = 0; ci < nc; ++ci) {
            const int col = list_s[row][gg][ci];
            float p = 0.f;
            for (int j = lane; j < KDIM; j += 64)
                p += x[(size_t)grow * KDIM + j] * W[(size_t)col * KDIM + j];
#pragma unroll
            for (int off = 32; off >= 1; off >>= 1) p += __shfl_xor(p, off);
            p += b[col];
            if (p > bestv || (p == bestv && col < bestc)) { bestv = p; bestc = col; }
        }
        if (lane == 0) {
            code_s[row][gg] = bestc;
            atomicAdd(&counts[bestc], 1.f);
        }
    }
    __syncthreads();

    // E7: gather xq for this block's 32 rows (codebook rows are L2-resident)
    {
#pragma unroll
        for (int u = 0; u < 4; ++u) {
            const int f   = tid + u * 512;      // float4 index 0..2047
            const int row = f >> 6;
            const int c   = f & 63;
            const int gg  = c >> 5;
            const int d4  = (c & 31) * 4;
            const int k   = code_s[row][gg];    // global col = g*320+v
            const float4 v = *(const float4*)(codebook + (size_t)k * DSZ + d4);
            *(float4*)(xq + (size_t)(row0 + row) * (GSZ * DSZ) + gg * DSZ + d4) = v;
        }
    }
}

// ---------------- perplexities + constant ----------------
__global__ __launch_bounds__(640) void finalize_k(
    const float* __restrict__ counts, const float* __restrict__ probs,
    float* __restrict__ out_scalars) {
    __shared__ float se_c[GSZ], se_p[GSZ];
    const int t = threadIdx.x;
    if (t < GSZ) { se_c[t] = 0.f; se_p[t] = 0.f; }
    __syncthreads();
    const int g = t / VSZ;
    const float hp = counts[t] * (1.f / (float)NROWS);
    const float ap = probs[t]  * (1.f / (float)NROWS);
    float tc = hp * logf(hp + 1e-7f);
    float tp = ap * logf(ap + 1e-7f);
#pragma unroll
    for (int off = 32; off >= 1; off >>= 1) {
        tc += __shfl_xor(tc, off);
        tp += __shfl_xor(tp, off);
    }
    if ((t & 63) == 0) { atomicAdd(&se_c[g], tc); atomicAdd(&se_p[g], tp); }
    __syncthreads();
    if (t == 0) {
        out_scalars[0] = (float)NCOL;
        out_scalars[1] = expf(-se_c[0]) + expf(-se_c[1]);
        out_scalars[2] = expf(-se_p[0]) + expf(-se_p[1]);
    }
}

extern "C" void kernel_launch(void* const* d_in, const int* in_sizes, int n_in,
                              void* d_out, int out_size, void* d_ws, size_t ws_size,
                              hipStream_t stream) {
    const float* x        = (const float*)d_in[0];
    const float* W        = (const float*)d_in[1];
    const float* b        = (const float*)d_in[2];
    const float* codebook = (const float*)d_in[3];
    float* out = (float*)d_out;

    short* Wb     = (short*)d_ws;                              // 983040 B
    float* accf   = (float*)((char*)d_ws + 983040);            // counts[640] + probs[640]
    float* counts = accf;
    float* probs  = accf + NCOL;

    prep_w_k<<<dim3(120), dim3(512), 0, stream>>>(W, Wb, accf);
    fused_vq_k<<<dim3(NROWS / BM), dim3(512), 0, stream>>>(x, Wb, W, b, codebook,
                                                           counts, probs, out);
    finalize_k<<<dim3(1), dim3(640), 0, stream>>>(counts, probs, out + XQ_TOTAL);
}